// Round 1
// baseline (1373.741 us; speedup 1.0000x reference)
//
#include <hip/hip_runtime.h>
#include <cstdint>
#include <cmath>

#define WND 8
#define NB 16
#define NH 2048
#define NW 2048
#define HC (NH / WND)            // 256
#define WCC (NW / WND)           // 256
#define NCELLS (NB * HC * WCC)   // 1048576

// Exact JAX threefry2x32 (20 rounds), usable on host and device.
__host__ __device__ inline void tf2x32(uint32_t k0, uint32_t k1,
                                       uint32_t x0, uint32_t x1,
                                       uint32_t& o0, uint32_t& o1) {
  uint32_t k2 = k0 ^ k1 ^ 0x1BD11BDAu;
  x0 += k0; x1 += k1;
#define TFR(r) { x0 += x1; x1 = (x1 << (r)) | (x1 >> (32 - (r))); x1 ^= x0; }
  TFR(13) TFR(15) TFR(26) TFR(6)
  x0 += k1; x1 += k2 + 1u;
  TFR(17) TFR(29) TFR(16) TFR(24)
  x0 += k2; x1 += k0 + 2u;
  TFR(13) TFR(15) TFR(26) TFR(6)
  x0 += k0; x1 += k1 + 3u;
  TFR(17) TFR(29) TFR(16) TFR(24)
  x0 += k1; x1 += k2 + 4u;
  TFR(13) TFR(15) TFR(26) TFR(6)
  x0 += k2; x1 += k0 + 5u;
#undef TFR
  o0 = x0; o1 = x1;
}

__device__ __forceinline__ float unit_from_bits(uint32_t b) {
  // JAX _uniform: bitcast((bits>>9) | 0x3f800000) - 1.0f  in [0,1)
  return __uint_as_float((b >> 9) | 0x3F800000u) - 1.0f;
}

// Correctly-rounded fp32 natural log via double.
__device__ __forceinline__ float crlogf(float x) {
  return (float)log((double)x);
}

__global__ __launch_bounds__(256) void kp_kernel(
    const float* __restrict__ xin, const float* __restrict__ mpin,
    float* __restrict__ out,
    uint32_t kg0, uint32_t kg1, uint32_t kb0, uint32_t kb1) {
  const int wave = (blockIdx.x << 2) + (threadIdx.x >> 6);  // cell id [0, NCELLS)
  const int lane = threadIdx.x & 63;
  const int wc = wave & (WCC - 1);
  const int hc = (wave >> 8) & (HC - 1);
  const int b  = wave >> 16;

  const int ty = lane >> 3, tx = lane & 7;
  const size_t off = (((size_t)b * NH) + ((size_t)(hc << 3) + ty)) * NW
                     + (size_t)(wc << 3) + tx;
  const float xv = xin[off];
  const float mv = mpin[off];

  // ---- gumbel for this element (partitionable scheme: bits = o0 ^ o1 of
  // threefry(kg, (0, flat_index)) ) ----
  const uint32_t elem = (uint32_t)wave * 64u + (uint32_t)lane;
  uint32_t g0, g1;
  tf2x32(kg0, kg1, 0u, elem, g0, g1);
  const float ufl = unit_from_bits(g0 ^ g1);
  const float u = fmaxf(ufl, 1.17549435e-38f);    // minval = tiny
  const float t = -crlogf(u);                     // fp32 intermediate rounding
  const float g = -crlogf(t);

  // ---- argmax(x + g) with first-index tie-break (JAX argmax semantics) ----
  const float v = xv + g;
  float av = v; int ai = lane;
  #pragma unroll
  for (int d = 1; d < 64; d <<= 1) {
    float ov = __shfl_xor(av, d, 64);
    int   oi = __shfl_xor(ai, d, 64);
    if (ov > av || (ov == av && oi < ai)) { av = ov; ai = oi; }
  }

  // ---- log_softmax pieces ----
  float mx = xv;
  #pragma unroll
  for (int d = 1; d < 64; d <<= 1) mx = fmaxf(mx, __shfl_xor(mx, d, 64));
  float s = expf(xv - mx);
  #pragma unroll
  for (int d = 1; d < 64; d <<= 1) s += __shfl_xor(s, d, 64);

  // ---- window min of mask_padding ----
  float mnm = mv;
  #pragma unroll
  for (int d = 1; d < 64; d <<= 1) mnm = fminf(mnm, __shfl_xor(mnm, d, 64));

  // selected logit (broadcast from winning lane)
  const float l = __shfl(xv, ai, 64);
  const float cat_lp = (l - mx) - crlogf(s);

  // ---- uniform for the Bernoulli accept (key kb, counter (0, cell)) ----
  uint32_t u0, u1;
  tf2x32(kb0, kb1, 0u, (uint32_t)wave, u0, u1);
  const float uu = unit_from_bits(u0 ^ u1);       // minval=0,maxval=1 -> identity

  const double sd = 1.0 / (1.0 + exp(-(double)l));
  const float sig = (float)sd;
  const bool acc = uu < sig;

  // log_sigmoid(l) = -(max(-l,0) + log1p(exp(-|l|)))
  const float lse = log1pf(expf(-fabsf(l)));
  const float ls_pos = -(fmaxf(-l, 0.0f) + lse);
  const float ls_neg = -(fmaxf( l, 0.0f) + lse);
  const float bern = acc ? ls_pos : ls_neg;
  const float lp = cat_lp + bern;

  if (lane == 0) {
    const int ci = wave;
    // keypoints [B,Hc,Wc,2] with (x, y) order (flipped)
    out[2 * (size_t)ci]     = (float)((wc << 3) + (ai & 7));
    out[2 * (size_t)ci + 1] = (float)((hc << 3) + (ai >> 3));
    out[(size_t)2 * NCELLS + ci] = lp;                     // log_probs
    out[(size_t)3 * NCELLS + ci] = acc ? 1.0f : 0.0f;      // mask
    out[(size_t)4 * NCELLS + ci] = mnm;                    // mp_grid
    out[(size_t)5 * NCELLS + ci] = l;                      // logits_selected
  }
}

extern "C" void kernel_launch(void* const* d_in, const int* in_sizes, int n_in,
                              void* d_out, int out_size, void* d_ws, size_t ws_size,
                              hipStream_t stream) {
  const float* x  = (const float*)d_in[0];
  const float* mp = (const float*)d_in[1];
  float* out = (float*)d_out;

  // Derive kg, kb exactly as jax.random.split(jax.random.key(42)) with
  // threefry_partitionable=True: key i = threefry(root, (0, i)) both outputs.
  uint32_t kg0, kg1, kb0, kb1;
  tf2x32(0u, 42u, 0u, 0u, kg0, kg1);
  tf2x32(0u, 42u, 0u, 1u, kb0, kb1);

  const int blocks = NCELLS / 4;  // 4 waves (cells) per 256-thread block
  kp_kernel<<<blocks, 256, 0, stream>>>(x, mp, out, kg0, kg1, kb0, kb1);
}

// Round 2
// 588.629 us; speedup vs baseline: 2.3338x; 2.3338x over previous
//
#include <hip/hip_runtime.h>
#include <cstdint>
#include <cmath>

#define WND 8
#define NB 16
#define NH 2048
#define NW 2048
#define HC (NH / WND)            // 256
#define WCC (NW / WND)           // 256
#define NCELLS (NB * HC * WCC)   // 1048576

#define TINYF 1.17549435e-38f
#define ETA 3e-5f               // guard band: >> fp32-log-chain deviation (~5e-6)

// Exact JAX threefry2x32 (20 rounds), usable on host and device.
__host__ __device__ inline void tf2x32(uint32_t k0, uint32_t k1,
                                       uint32_t x0, uint32_t x1,
                                       uint32_t& o0, uint32_t& o1) {
  uint32_t k2 = k0 ^ k1 ^ 0x1BD11BDAu;
  x0 += k0; x1 += k1;
#define TFR(r) { x0 += x1; x1 = (x1 << (r)) | (x1 >> (32 - (r))); x1 ^= x0; }
  TFR(13) TFR(15) TFR(26) TFR(6)
  x0 += k1; x1 += k2 + 1u;
  TFR(17) TFR(29) TFR(16) TFR(24)
  x0 += k2; x1 += k0 + 2u;
  TFR(13) TFR(15) TFR(26) TFR(6)
  x0 += k0; x1 += k1 + 3u;
  TFR(17) TFR(29) TFR(16) TFR(24)
  x0 += k1; x1 += k2 + 4u;
  TFR(13) TFR(15) TFR(26) TFR(6)
  x0 += k2; x1 += k0 + 5u;
#undef TFR
  o0 = x0; o1 = x1;
}

__device__ __forceinline__ float unit_from_bits(uint32_t b) {
  // JAX _uniform: bitcast((bits>>9) | 0x3f800000) - 1.0f  in [0,1)
  return __uint_as_float((b >> 9) | 0x3F800000u) - 1.0f;
}

// Correctly-rounded fp32 natural log via double (exact fallback path only).
__device__ __forceinline__ float crlogf(float x) {
  return (float)log((double)x);
}

__global__ __launch_bounds__(256) void kp_kernel(
    const float* __restrict__ xin, const float* __restrict__ mpin,
    float* __restrict__ out,
    uint32_t kg0, uint32_t kg1, uint32_t kb0, uint32_t kb1) {
  const int cell = blockIdx.x * 256 + threadIdx.x;   // one THREAD per cell
  const int wc = cell & (WCC - 1);
  const int hc = (cell >> 8) & (HC - 1);
  const int b  = cell >> 16;
  const size_t base = (((size_t)b * NH) + (size_t)(hc << 3)) * NW + (size_t)(wc << 3);

  const uint32_t ebase = (uint32_t)cell << 6;

  float m1 = -INFINITY;   // best v = x + gumbel
  float m2 = -INFINITY;   // second-best v (value only) — guard band
  int   i1 = 0;           // argmax index within cell (first-index tie-break)
  float lsel = 0.0f;      // x at argmax
  float s0 = 0.0f;        // sum of exp(x) (no max shift; x~N(0,1), no overflow)
  float mnm = INFINITY;   // window min of mask_padding

  #pragma unroll 2
  for (int r = 0; r < 8; ++r) {
    const size_t ro = base + (size_t)r * NW;
    const float4 a0 = *(const float4*)(xin + ro);
    const float4 a1 = *(const float4*)(xin + ro + 4);
    const float4 p0 = *(const float4*)(mpin + ro);
    const float4 p1 = *(const float4*)(mpin + ro + 4);
    mnm = fminf(mnm, fminf(fminf(fminf(p0.x, p0.y), fminf(p0.z, p0.w)),
                           fminf(fminf(p1.x, p1.y), fminf(p1.z, p1.w))));
    const float xs[8] = {a0.x, a0.y, a0.z, a0.w, a1.x, a1.y, a1.z, a1.w};
    #pragma unroll
    for (int c = 0; c < 8; ++c) {
      const float xv = xs[c];
      uint32_t g0, g1;
      tf2x32(kg0, kg1, 0u, ebase + (uint32_t)(r * 8 + c), g0, g1);
      const float u = fmaxf(unit_from_bits(g0 ^ g1), TINYF);
      const float t = -logf(u);          // accurate ocml logf (~1 ulp)
      const float g = -logf(t);
      const float v = xv + g;
      s0 += __expf(xv);
      if (v > m1) { m2 = m1; m1 = v; i1 = r * 8 + c; lsel = xv; }
      else        { m2 = fmaxf(m2, v); }
    }
  }

  // Near-tie guard: if top-2 gap is within the fp32-log error band, redo this
  // cell with the exact (fp64, correctly-rounded-to-fp32) R0 path.
  if (m1 - m2 <= ETA) {
    float best = -INFINITY; int bi = 0; float bl = 0.0f;
    for (int j = 0; j < 64; ++j) {
      const float xv = xin[base + (size_t)(j >> 3) * NW + (size_t)(j & 7)];
      uint32_t g0, g1;
      tf2x32(kg0, kg1, 0u, ebase + (uint32_t)j, g0, g1);
      const float u = fmaxf(unit_from_bits(g0 ^ g1), TINYF);
      const float t = -crlogf(u);
      const float g = -crlogf(t);
      const float v = xv + g;
      if (v > best) { best = v; bi = j; bl = xv; }
    }
    i1 = bi; lsel = bl;
  }

  // ---- per-cell epilogue (amortized 64x vs wave-per-cell) ----
  const float cat_lp = lsel - logf(s0);   // == (l - mx) - log(sum exp(x-mx))

  uint32_t u0, u1;
  tf2x32(kb0, kb1, 0u, (uint32_t)cell, u0, u1);
  const float uu = unit_from_bits(u0 ^ u1);

  const double sd = 1.0 / (1.0 + exp(-(double)lsel));  // exact R0 sigmoid
  const bool acc = uu < (float)sd;

  const float lse = log1pf(expf(-fabsf(lsel)));
  const float ls_pos = -(fmaxf(-lsel, 0.0f) + lse);
  const float ls_neg = -(fmaxf( lsel, 0.0f) + lse);
  const float lp = cat_lp + (acc ? ls_pos : ls_neg);

  const size_t ci = (size_t)cell;
  out[2 * ci]     = (float)((wc << 3) + (i1 & 7));       // keypoint x
  out[2 * ci + 1] = (float)((hc << 3) + (i1 >> 3));      // keypoint y
  out[(size_t)2 * NCELLS + ci] = lp;                     // log_probs
  out[(size_t)3 * NCELLS + ci] = acc ? 1.0f : 0.0f;      // mask
  out[(size_t)4 * NCELLS + ci] = mnm;                    // mp_grid
  out[(size_t)5 * NCELLS + ci] = lsel;                   // logits_selected
}

extern "C" void kernel_launch(void* const* d_in, const int* in_sizes, int n_in,
                              void* d_out, int out_size, void* d_ws, size_t ws_size,
                              hipStream_t stream) {
  const float* x  = (const float*)d_in[0];
  const float* mp = (const float*)d_in[1];
  float* out = (float*)d_out;

  // jax.random.split(jax.random.key(42)), threefry_partitionable:
  // child i = both outputs of threefry(root, (0, i)).
  uint32_t kg0, kg1, kb0, kb1;
  tf2x32(0u, 42u, 0u, 0u, kg0, kg1);
  tf2x32(0u, 42u, 0u, 1u, kb0, kb1);

  kp_kernel<<<NCELLS / 256, 256, 0, stream>>>(x, mp, out, kg0, kg1, kb0, kb1);
}

// Round 3
// 587.100 us; speedup vs baseline: 2.3399x; 1.0026x over previous
//
#include <hip/hip_runtime.h>
#include <cstdint>
#include <cmath>

#define WND 8
#define NB 16
#define NH 2048
#define NW 2048
#define HC (NH / WND)            // 256
#define WCC (NW / WND)           // 256
#define NCELLS (NB * HC * WCC)   // 1048576

#define TINYF 1.17549435e-38f
// Guard band for the fast-log gumbel chain vs the reference fp32 chain.
// Worst-case per-element deviation delta ~1.4e-5 (hw v_log abs err 2^-22,
// series region rel err ~2e-7); guard needs 2*delta -> 6e-5 with margin.
#define ETA 6e-5f
#define NLN2 -0.69314718055994530942f

// Exact JAX threefry2x32 (20 rounds), usable on host and device.
__host__ __device__ inline void tf2x32(uint32_t k0, uint32_t k1,
                                       uint32_t x0, uint32_t x1,
                                       uint32_t& o0, uint32_t& o1) {
  uint32_t k2 = k0 ^ k1 ^ 0x1BD11BDAu;
  x0 += k0; x1 += k1;
#define TFR(r) { x0 += x1; x1 = (x1 << (r)) | (x1 >> (32 - (r))); x1 ^= x0; }
  TFR(13) TFR(15) TFR(26) TFR(6)
  x0 += k1; x1 += k2 + 1u;
  TFR(17) TFR(29) TFR(16) TFR(24)
  x0 += k2; x1 += k0 + 2u;
  TFR(13) TFR(15) TFR(26) TFR(6)
  x0 += k0; x1 += k1 + 3u;
  TFR(17) TFR(29) TFR(16) TFR(24)
  x0 += k1; x1 += k2 + 4u;
  TFR(13) TFR(15) TFR(26) TFR(6)
  x0 += k2; x1 += k0 + 5u;
#undef TFR
  o0 = x0; o1 = x1;
}

__device__ __forceinline__ float unit_from_bits(uint32_t b) {
  // JAX _uniform: bitcast((bits>>9) | 0x3f800000) - 1.0f  in [0,1)
  return __uint_as_float((b >> 9) | 0x3F800000u) - 1.0f;
}

// Correctly-rounded fp32 natural log via double (exact fallback path only).
__device__ __forceinline__ float crlogf(float x) {
  return (float)log((double)x);
}

// Fast gumbel: g = -log(-log(u)) via hw v_log_f32 (log2), with a branchless
// series for u near 1 where hw log's ~2^-22 ABSOLUTE error would blow up the
// relative error of the tiny first-log result. g only decides argmax; the
// ETA guard + exact fallback covers the deviation band.
__device__ __forceinline__ float fast_gumbel(float u) {
  const float t_hw = __builtin_amdgcn_logf(u) * NLN2;          // -ln(u)
  const float e = 1.0f - u;                                    // exact for u>=0.5
  // -log(1-e) = e*(1 + e*(1/2 + e*(1/3 + e*(1/4)))) ; trunc err < 2e-7 rel
  const float t_ser = e * fmaf(e, fmaf(e, fmaf(e, 0.25f, 0.33333333333333f),
                                       0.5f), 1.0f);
  const float t = (e < 0.03125f) ? t_ser : t_hw;
  return __builtin_amdgcn_logf(t) * NLN2;                      // -ln(t)
}

__global__ __launch_bounds__(256) void kp_kernel(
    const float* __restrict__ xin, const float* __restrict__ mpin,
    float* __restrict__ out,
    uint32_t kg0, uint32_t kg1, uint32_t kb0, uint32_t kb1) {
  const int cell = blockIdx.x * 256 + threadIdx.x;   // one THREAD per cell
  const int wc = cell & (WCC - 1);
  const int hc = (cell >> 8) & (HC - 1);
  const int b  = cell >> 16;
  const size_t base = (((size_t)b * NH) + (size_t)(hc << 3)) * NW + (size_t)(wc << 3);

  const uint32_t ebase = (uint32_t)cell << 6;

  float m1 = -INFINITY;   // best v = x + gumbel (fast chain)
  float m2 = -INFINITY;   // second-best v — guard band
  int   i1 = 0;           // argmax index within cell (first-index tie-break)
  float lsel = 0.0f;      // x at argmax
  float s0 = 0.0f;        // sum of exp(x) (x~N(0,1): no overflow, no shift)
  float mnm = INFINITY;   // window min of mask_padding

  // software pipeline: prefetch next x row + this mp row, then process
  float4 a0 = *(const float4*)(xin + base);
  float4 a1 = *(const float4*)(xin + base + 4);
  #pragma unroll
  for (int r = 0; r < 8; ++r) {
    float4 n0, n1;
    if (r < 7) {
      n0 = *(const float4*)(xin + base + (size_t)(r + 1) * NW);
      n1 = *(const float4*)(xin + base + (size_t)(r + 1) * NW + 4);
    }
    const float4 p0 = *(const float4*)(mpin + base + (size_t)r * NW);
    const float4 p1 = *(const float4*)(mpin + base + (size_t)r * NW + 4);

    const float xs[8] = {a0.x, a0.y, a0.z, a0.w, a1.x, a1.y, a1.z, a1.w};
    #pragma unroll
    for (int c = 0; c < 8; ++c) {
      const float xv = xs[c];
      uint32_t g0, g1;
      tf2x32(kg0, kg1, 0u, ebase + (uint32_t)(r * 8 + c), g0, g1);
      const float u = fmaxf(unit_from_bits(g0 ^ g1), TINYF);
      const float g = fast_gumbel(u);
      const float v = xv + g;
      s0 += __expf(xv);
      if (v > m1) { m2 = m1; m1 = v; i1 = r * 8 + c; lsel = xv; }
      else        { m2 = fmaxf(m2, v); }
    }

    mnm = fminf(mnm, fminf(fminf(fminf(p0.x, p0.y), fminf(p0.z, p0.w)),
                           fminf(fminf(p1.x, p1.y), fminf(p1.z, p1.w))));
    a0 = n0; a1 = n1;
  }

  // Near-tie guard: if top-2 fast gap is within the deviation band, redo this
  // cell with the exact (fp64, correctly-rounded-to-fp32) reference path.
  if (m1 - m2 <= ETA) {
    float best = -INFINITY; int bi = 0; float bl = 0.0f;
    for (int j = 0; j < 64; ++j) {
      const float xv = xin[base + (size_t)(j >> 3) * NW + (size_t)(j & 7)];
      uint32_t g0, g1;
      tf2x32(kg0, kg1, 0u, ebase + (uint32_t)j, g0, g1);
      const float u = fmaxf(unit_from_bits(g0 ^ g1), TINYF);
      const float t = -crlogf(u);
      const float g = -crlogf(t);
      const float v = xv + g;
      if (v > best) { best = v; bi = j; bl = xv; }
    }
    i1 = bi; lsel = bl;
  }

  // ---- per-cell epilogue (amortized 64x) ----
  const float cat_lp = lsel - logf(s0);   // == (l - mx) - log(sum exp(x-mx))

  uint32_t u0, u1;
  tf2x32(kb0, kb1, 0u, (uint32_t)cell, u0, u1);
  const float uu = unit_from_bits(u0 ^ u1);

  const double sd = 1.0 / (1.0 + exp(-(double)lsel));  // exact ref sigmoid
  const bool acc = uu < (float)sd;

  const float lse = log1pf(expf(-fabsf(lsel)));
  const float ls_pos = -(fmaxf(-lsel, 0.0f) + lse);
  const float ls_neg = -(fmaxf( lsel, 0.0f) + lse);
  const float lp = cat_lp + (acc ? ls_pos : ls_neg);

  const size_t ci = (size_t)cell;
  float2 kp;
  kp.x = (float)((wc << 3) + (i1 & 7));                  // keypoint x
  kp.y = (float)((hc << 3) + (i1 >> 3));                 // keypoint y
  *(float2*)(out + 2 * ci) = kp;
  out[(size_t)2 * NCELLS + ci] = lp;                     // log_probs
  out[(size_t)3 * NCELLS + ci] = acc ? 1.0f : 0.0f;      // mask
  out[(size_t)4 * NCELLS + ci] = mnm;                    // mp_grid
  out[(size_t)5 * NCELLS + ci] = lsel;                   // logits_selected
}

extern "C" void kernel_launch(void* const* d_in, const int* in_sizes, int n_in,
                              void* d_out, int out_size, void* d_ws, size_t ws_size,
                              hipStream_t stream) {
  const float* x  = (const float*)d_in[0];
  const float* mp = (const float*)d_in[1];
  float* out = (float*)d_out;

  // jax.random.split(jax.random.key(42)), threefry_partitionable:
  // child i = both outputs of threefry(root, (0, i)).
  uint32_t kg0, kg1, kb0, kb1;
  tf2x32(0u, 42u, 0u, 0u, kg0, kg1);
  tf2x32(0u, 42u, 0u, 1u, kb0, kb1);

  kp_kernel<<<NCELLS / 256, 256, 0, stream>>>(x, mp, out, kg0, kg1, kb0, kb1);
}